// Round 9
// baseline (1355.978 us; speedup 1.0000x reference)
//
#include <hip/hip_runtime.h>
#include <hip/hip_bf16.h>
#include <math.h>

#define NB 8192
#define NS 12
#define NH 8
#define NDK 64
#define NDM 512

typedef __attribute__((ext_vector_type(8))) short bf16x8;
typedef __attribute__((ext_vector_type(4))) float f32x4;

static __device__ __forceinline__ short f2bfb(float x) {
    __hip_bfloat16 h = __float2bfloat16(x);
    return *(short*)&h;
}

__global__ __launch_bounds__(512) void wcvt_kernel(const float* __restrict__ W,
                                                   __hip_bfloat16* __restrict__ Wb) {
    int i = blockIdx.x * 512 + threadIdx.x;
    Wb[i] = __float2bfloat16(W[i]);
}

// conv for one (h, d) position: neighbor-h rows loaded straight from global
// (L1/L2-cached), d+-1 via shfl. Returns 12 output channels in o0..o2.
static __device__ __forceinline__ void conv_hd(
    const float* __restrict__ xb, int h, int d,
    const float wt[3][12][12], const float* bconv,
    f32x4& o0, f32x4& o1, f32x4& o2)
{
    const float fm = (h > 0) ? 1.f : 0.f;
    const float fp = (h < 7) ? 1.f : 0.f;
    const float* pa = xb + h * 64 + d;
    const float* pm = xb + (h > 0 ? h - 1 : h) * 64 + d;
    const float* pp = xb + (h < 7 ? h + 1 : h) * 64 + d;
    o0 = *(const f32x4*)&bconv[0];
    o1 = *(const f32x4*)&bconv[4];
    o2 = *(const f32x4*)&bconv[8];
    #pragma unroll 3
    for (int s2 = 0; s2 < 12; ++s2) {
        float a  = pa[s2 * 512];
        float am = pm[s2 * 512] * fm;
        float ap = pp[s2 * 512] * fp;
        float n0 = a + am + ap;
        float nm = __shfl_up(n0, 1);   if (d == 0)  nm = 0.f;   // zero-pad d=-1
        float np = __shfl_down(n0, 1); if (d == 63) np = 0.f;   // zero-pad d=64
        const f32x4* w0 = (const f32x4*)&wt[0][s2][0];
        const f32x4* w1 = (const f32x4*)&wt[1][s2][0];
        const f32x4* w2 = (const f32x4*)&wt[2][s2][0];
        o0 += w0[0] * nm + w1[0] * n0 + w2[0] * np;
        o1 += w0[1] * nm + w1[1] * n0 + w2[1] * np;
        o2 += w0[2] * nm + w1[2] * n0 + w2[2] * np;
    }
}

// ---------------- fully fused: conv + attention + projection ----------------
// block = 4 batches, 8 waves. wave -> (bb = w&3, hbase = (w>>2)*4), 4 head-tasks.
__global__ __launch_bounds__(512) void fused5_kernel(
    const float* __restrict__ gq, const float* __restrict__ gk, const float* __restrict__ gv,
    const int* __restrict__ gmask, const float* __restrict__ gcw, const float* __restrict__ gcb,
    const __hip_bfloat16* __restrict__ Wb, const float* __restrict__ gbo,
    float* __restrict__ gout)
{
    // first 36864 B: per-wave q/k staging [16][72] bf16 x2; after barrier: abuf [48][520] bf16
    __shared__ __align__(16) short ovbuf[24960];        // 49920 B
    __shared__ __align__(16) float probs[NH][12][16];   // 6144 B
    __shared__ __align__(16) float wt[3][12][12];       // 1728 B
    __shared__ __align__(16) float bconv[12];
    // total ~57.9 KB -> 2 blocks/CU

    const int tid = threadIdx.x;
    const int w   = tid >> 6;
    const int ln  = tid & 63;
    const int d   = ln;
    const int rA  = ln & 15, g = ln >> 4;

    const int b0    = blockIdx.x * 4;
    const int bb    = w & 3;
    const int b     = b0 + bb;
    const int hbase = (w >> 2) * 4;

    if (tid < 432) {
        int t = tid / 144, rem = tid - t * 144;
        int s2 = rem / 12, s = rem - s2 * 12;
        wt[t][s2][s] = gcw[s * 36 + s2 * 3 + t];
    } else if (tid < 444) {
        bconv[tid - 432] = gcb[tid - 432];
    }
    __syncthreads();

    const float* xq = gq + (size_t)b * (NS * NDM);
    const float* xk = gk + (size_t)b * (NS * NDM);
    const float* xv = gv + (size_t)b * (NS * NDM);
    const int* mrow = gmask + (size_t)b * 144;

    short* stq = ovbuf + w * 2304;   // [16][72]
    short* stk = stq + 1152;

    unsigned pvp[24];                // 4 tasks x 12 bf16 (packed), statically indexed

    #pragma unroll
    for (int t = 0; t < 4; ++t) {
        const int h = hbase + t;
        f32x4 o0, o1, o2;

        // ---- conv q -> wave-local staging ----
        conv_hd(xq, h, d, wt, bconv, o0, o1, o2);
        #pragma unroll
        for (int s = 0; s < 4; ++s) {
            stq[s * 72 + d]       = f2bfb(o0[s]);
            stq[(s + 4) * 72 + d] = f2bfb(o1[s]);
            stq[(s + 8) * 72 + d] = f2bfb(o2[s]);
        }
        __builtin_amdgcn_sched_barrier(0);

        // ---- conv k -> wave-local staging ----
        conv_hd(xk, h, d, wt, bconv, o0, o1, o2);
        #pragma unroll
        for (int s = 0; s < 4; ++s) {
            stk[s * 72 + d]       = f2bfb(o0[s]);
            stk[(s + 4) * 72 + d] = f2bfb(o1[s]);
            stk[(s + 8) * 72 + d] = f2bfb(o2[s]);
        }
        __builtin_amdgcn_sched_barrier(0);

        // ---- conv v -> registers ----
        float vv[12];
        conv_hd(xv, h, d, wt, bconv, o0, o1, o2);
        #pragma unroll
        for (int s = 0; s < 4; ++s) { vv[s] = o0[s]; vv[s + 4] = o1[s]; vv[s + 8] = o2[s]; }
        __builtin_amdgcn_sched_barrier(0);

        // ---- scores via MFMA (wave-local staging; rows 12..15 garbage -> masked) ----
        bf16x8 aq0 = *(const bf16x8*)(stq + rA * 72 + g * 8);
        bf16x8 aq1 = *(const bf16x8*)(stq + rA * 72 + 32 + g * 8);
        bf16x8 bk0 = *(const bf16x8*)(stk + rA * 72 + g * 8);
        bf16x8 bk1 = *(const bf16x8*)(stk + rA * 72 + 32 + g * 8);
        f32x4 sc = {0.f, 0.f, 0.f, 0.f};
        sc = __builtin_amdgcn_mfma_f32_16x16x32_bf16(aq0, bk0, sc, 0, 0, 0);
        sc = __builtin_amdgcn_mfma_f32_16x16x32_bf16(aq1, bk1, sc, 0, 0, 0);

        // ---- mask + softmax (row qi in 16-lane groups; col kj = lane&15) ----
        const int kj = rA;
        #pragma unroll
        for (int r = 0; r < 4; ++r) {
            int qi = g * 4 + r;
            float s = sc[r] * 0.125f;
            if (kj >= 12) s = -INFINITY;
            else if (qi < 12 && mrow[qi * 12 + kj] == 0) s = -1e9f;
            float m = s;
            #pragma unroll
            for (int off = 1; off < 16; off <<= 1) m = fmaxf(m, __shfl_xor(m, off, 16));
            float e = __expf(s - m);
            float sum = e;
            #pragma unroll
            for (int off = 1; off < 16; off <<= 1) sum += __shfl_xor(sum, off, 16);
            if (qi < 12) probs[w][qi][kj] = e / sum;
        }

        // ---- PV -> packed bf16 registers (static indices) ----
        #pragma unroll
        for (int qj = 0; qj < 6; ++qj) {
            const f32x4* pr0 = (const f32x4*)&probs[w][2 * qj][0];
            const f32x4* pr1 = (const f32x4*)&probs[w][2 * qj + 1][0];
            f32x4 a0 = pr0[0], a1 = pr0[1], a2 = pr0[2];
            f32x4 c0 = pr1[0], c1 = pr1[1], c2 = pr1[2];
            float acc0 = 0.f, acc1 = 0.f;
            #pragma unroll
            for (int j = 0; j < 4; ++j) {
                acc0 += a0[j] * vv[j] + a1[j] * vv[j + 4] + a2[j] * vv[j + 8];
                acc1 += c0[j] * vv[j] + c1[j] * vv[j + 4] + c2[j] * vv[j + 8];
            }
            pvp[t * 6 + qj] = (unsigned)(unsigned short)f2bfb(acc0)
                            | ((unsigned)(unsigned short)f2bfb(acc1) << 16);
        }
        __builtin_amdgcn_sched_barrier(0);
    }

    __syncthreads();   // all waves done with staging reads; ovbuf becomes abuf

    // ---- dump PV rows -> abuf [48][520] ----
    #pragma unroll
    for (int t = 0; t < 4; ++t) {
        const int h = hbase + t;
        #pragma unroll
        for (int qj = 0; qj < 6; ++qj) {
            unsigned p = pvp[t * 6 + qj];
            ovbuf[(bb * 12 + 2 * qj) * 520 + h * 64 + d]     = (short)(p & 0xffff);
            ovbuf[(bb * 12 + 2 * qj + 1) * 520 + h * 64 + d] = (short)(p >> 16);
        }
    }
    __syncthreads();

    // ---- projection: C[48 x 512] = A * W^T + b, W-frag reused across 3 m-tiles ----
    {
        const short* Ws = (const short*)Wb;
        const int n_lane = w * 64 + rA;
        f32x4 acc[3][4] = {};
        #pragma unroll 4
        for (int kk = 0; kk < 16; ++kk) {
            int k0 = kk * 32 + g * 8;
            bf16x8 af0 = *(const bf16x8*)(ovbuf + (rA)      * 520 + k0);
            bf16x8 af1 = *(const bf16x8*)(ovbuf + (16 + rA) * 520 + k0);
            bf16x8 af2 = *(const bf16x8*)(ovbuf + (32 + rA) * 520 + k0);
            #pragma unroll
            for (int i = 0; i < 4; ++i) {
                bf16x8 bfg = *(const bf16x8*)(Ws + (size_t)(n_lane + i * 16) * NDM + k0);
                acc[0][i] = __builtin_amdgcn_mfma_f32_16x16x32_bf16(af0, bfg, acc[0][i], 0, 0, 0);
                acc[1][i] = __builtin_amdgcn_mfma_f32_16x16x32_bf16(af1, bfg, acc[1][i], 0, 0, 0);
                acc[2][i] = __builtin_amdgcn_mfma_f32_16x16x32_bf16(af2, bfg, acc[2][i], 0, 0, 0);
            }
        }
        float bias[4];
        #pragma unroll
        for (int i = 0; i < 4; ++i) bias[i] = gbo[w * 64 + i * 16 + rA];
        #pragma unroll
        for (int m = 0; m < 3; ++m) {
            #pragma unroll
            for (int i = 0; i < 4; ++i) {
                int n = w * 64 + i * 16 + rA;
                #pragma unroll
                for (int r = 0; r < 4; ++r) {
                    int mg = m * 16 + g * 4 + r;        // 0..47 (all real rows)
                    int bi = mg / 12, qi = mg - bi * 12;
                    gout[(((size_t)(b0 + bi)) * NS + qi) * NDM + n] = acc[m][i][r] + bias[i];
                }
            }
        }
    }
}

extern "C" void kernel_launch(void* const* d_in, const int* in_sizes, int n_in,
                              void* d_out, int out_size, void* d_ws, size_t ws_size,
                              hipStream_t stream) {
    const float* q    = (const float*)d_in[0];
    const float* k    = (const float*)d_in[1];
    const float* v    = (const float*)d_in[2];
    const int*   mask = (const int*)d_in[3];
    const float* cw   = (const float*)d_in[4];
    const float* cb   = (const float*)d_in[5];
    const float* W    = (const float*)d_in[6];
    const float* bo   = (const float*)d_in[7];

    __hip_bfloat16* Wb = (__hip_bfloat16*)d_ws;   // 512 KB bf16 copy of W_out

    hipLaunchKernelGGL(wcvt_kernel, dim3(512), dim3(512), 0, stream, W, Wb);
    hipLaunchKernelGGL(fused5_kernel, dim3(NB / 4), dim3(512), 0, stream,
                       q, k, v, mask, cw, cb, Wb, bo, (float*)d_out);
}

// Round 10
// 425.856 us; speedup vs baseline: 3.1841x; 3.1841x over previous
//
#include <hip/hip_runtime.h>
#include <hip/hip_bf16.h>
#include <math.h>

#define NB 8192
#define NS 12
#define NH 8
#define NDK 64
#define NDM 512

typedef __attribute__((ext_vector_type(8))) short bf16x8;
typedef __attribute__((ext_vector_type(4))) float f32x4;

static __device__ __forceinline__ short f2bfb(float x) {
    __hip_bfloat16 h = __float2bfloat16(x);
    return *(short*)&h;
}
static __device__ __forceinline__ float bfb2f(short s) {
    unsigned u = ((unsigned)(unsigned short)s) << 16;
    return __uint_as_float(u);
}

__global__ __launch_bounds__(512) void wcvt_kernel(const float* __restrict__ W,
                                                   __hip_bfloat16* __restrict__ Wb) {
    int i = blockIdx.x * 512 + threadIdx.x;
    Wb[i] = __float2bfloat16(W[i]);
}

// ---------------- Kernel A: conv, 4 d-columns per thread ----------------
// thread = (b, h, d0..d0+3). h+-1 rows from global (float4, L1/L2-cached),
// d+-1 via 2 width-16 shfls per s2. Block = 256 thr = 2 batches x 8 h x 16 d4.
// qc/kc layout: [B][H][12][64] bf16 ; vc layout: [B][H][64][12] bf16
__global__ __launch_bounds__(256) void conv4_kernel(
    const float* __restrict__ gq, const float* __restrict__ gk, const float* __restrict__ gv,
    const float* __restrict__ gcw, const float* __restrict__ gcb,
    short* __restrict__ qc, short* __restrict__ kc, short* __restrict__ vc)
{
    __shared__ __align__(16) float wt[3][12][12];   // [tap][in_ch][out_ch]
    __shared__ __align__(16) float bconv[12];

    const int tid = threadIdx.x;
    for (int i = tid; i < 444; i += 256) {
        if (i < 432) {
            int t = i / 144, rem = i - t * 144;
            int s2 = rem / 12, s = rem - s2 * 12;
            wt[t][s2][s] = gcw[s * 36 + s2 * 3 + t];
        } else {
            bconv[i - 432] = gcb[i - 432];
        }
    }
    __syncthreads();

    const int t3   = blockIdx.y;                 // 0=q, 1=k, 2=v
    const int lane = tid & 63;
    const int w    = tid >> 6;                   // 0..3
    const int d4   = lane & 15;
    const int d0   = d4 * 4;
    const int h    = ((w & 1) << 2) + (lane >> 4);       // 0..7
    const int b    = blockIdx.x * 2 + (w >> 1);

    const float* src = (t3 == 0) ? gq : (t3 == 1) ? gk : gv;
    const float* xb  = src + (size_t)b * (NS * NDM);

    const float fm = (h > 0) ? 1.f : 0.f;
    const float fp = (h < 7) ? 1.f : 0.f;
    const float4* pa = (const float4*)(xb + h * 64 + d0);                  // +s2*128 (f4)
    const float4* pm = (const float4*)(xb + (h > 0 ? h - 1 : h) * 64 + d0);
    const float4* pp = (const float4*)(xb + (h < 7 ? h + 1 : h) * 64 + d0);

    f32x4 o[12];
    #pragma unroll
    for (int s = 0; s < 12; ++s) {
        float bs = bconv[s];
        o[s] = (f32x4){bs, bs, bs, bs};
    }

    #pragma unroll 2
    for (int s2 = 0; s2 < 12; ++s2) {
        float4 a  = pa[s2 * 128];
        float4 am = pm[s2 * 128];
        float4 ap = pp[s2 * 128];
        f32x4 ns;
        ns[0] = a.x + am.x * fm + ap.x * fp;
        ns[1] = a.y + am.y * fm + ap.y * fp;
        ns[2] = a.z + am.z * fm + ap.z * fp;
        ns[3] = a.w + am.w * fm + ap.w * fp;

        float prev = __shfl_up(ns[3], 1, 16);   if (d4 == 0)  prev = 0.f;  // d=-1 pad
        float next = __shfl_down(ns[0], 1, 16); if (d4 == 15) next = 0.f;  // d=64 pad
        f32x4 nsm = {prev, ns[0], ns[1], ns[2]};
        f32x4 nsp = {ns[1], ns[2], ns[3], next};

        #pragma unroll
        for (int tap = 0; tap < 3; ++tap) {
            const f32x4 nv = (tap == 0) ? nsm : (tap == 1) ? ns : nsp;
            #pragma unroll
            for (int G = 0; G < 3; ++G) {
                f32x4 wv = *(const f32x4*)&wt[tap][s2][G * 4];
                o[G * 4 + 0] += nv * wv[0];
                o[G * 4 + 1] += nv * wv[1];
                o[G * 4 + 2] += nv * wv[2];
                o[G * 4 + 3] += nv * wv[3];
            }
        }
    }

    if (t3 < 2) {
        short* dst = ((t3 == 0) ? qc : kc) + ((size_t)b * NH + h) * (NS * NDK) + d0;
        #pragma unroll
        for (int s = 0; s < 12; ++s) {
            short4 v;
            v.x = f2bfb(o[s][0]); v.y = f2bfb(o[s][1]);
            v.z = f2bfb(o[s][2]); v.w = f2bfb(o[s][3]);
            *(short4*)(dst + s * 64) = v;
        }
    } else {
        short* dstb = vc + (((size_t)b * NH + h) * NDK + d0) * NS;
        #pragma unroll
        for (int dd = 0; dd < 4; ++dd) {
            short4* dst = (short4*)(dstb + dd * NS);
            short4 p0, p1, p2;
            p0.x = f2bfb(o[0][dd]); p0.y = f2bfb(o[1][dd]); p0.z = f2bfb(o[2][dd]);  p0.w = f2bfb(o[3][dd]);
            p1.x = f2bfb(o[4][dd]); p1.y = f2bfb(o[5][dd]); p1.z = f2bfb(o[6][dd]);  p1.w = f2bfb(o[7][dd]);
            p2.x = f2bfb(o[8][dd]); p2.y = f2bfb(o[9][dd]); p2.z = f2bfb(o[10][dd]); p2.w = f2bfb(o[11][dd]);
            dst[0] = p0; dst[1] = p1; dst[2] = p2;
        }
    }
}

// ---------------- Kernel B: attention + projection for FOUR batches ----------------
__global__ __launch_bounds__(512) void attn2_kernel(
    const short* __restrict__ qc, const short* __restrict__ kc, const short* __restrict__ vc,
    const int* __restrict__ gmask, const __hip_bfloat16* __restrict__ Wb,
    const float* __restrict__ gbo, float* __restrict__ gout)
{
    __shared__ __align__(16) short abuf[48 * 520];      // 49920 B
    __shared__ __align__(16) float probs[NH][12][16];   // 6144 B

    const int tid = threadIdx.x;
    const int w   = tid >> 6;
    const int ln  = tid & 63;
    const int d   = ln;
    const int rA  = ln & 15, g = ln >> 4;

    const int b0    = blockIdx.x * 4;
    const int bb    = w & 3;
    const int b     = b0 + bb;
    const int hbase = (w >> 2) * 4;

    const int rAr = (rA < 12) ? rA : 0;

    for (int t = 0; t < 4; ++t) {
        const int h = hbase + t;
        const short* qs = qc + ((size_t)b * NH + h) * (NS * NDK);
        const short* ks = kc + ((size_t)b * NH + h) * (NS * NDK);
        bf16x8 aq0 = *(const bf16x8*)(qs + rAr * 64 + g * 8);
        bf16x8 aq1 = *(const bf16x8*)(qs + rAr * 64 + 32 + g * 8);
        bf16x8 bk0 = *(const bf16x8*)(ks + rAr * 64 + g * 8);
        bf16x8 bk1 = *(const bf16x8*)(ks + rAr * 64 + 32 + g * 8);
        f32x4 sc = {0.f, 0.f, 0.f, 0.f};
        sc = __builtin_amdgcn_mfma_f32_16x16x32_bf16(aq0, bk0, sc, 0, 0, 0);
        sc = __builtin_amdgcn_mfma_f32_16x16x32_bf16(aq1, bk1, sc, 0, 0, 0);

        float vv[12];
        {
            const short4* vp = (const short4*)(vc + (((size_t)b * NH + h) * NDK + d) * NS);
            short4 v0 = vp[0], v1 = vp[1], v2 = vp[2];
            vv[0] = bfb2f(v0.x); vv[1] = bfb2f(v0.y); vv[2]  = bfb2f(v0.z); vv[3]  = bfb2f(v0.w);
            vv[4] = bfb2f(v1.x); vv[5] = bfb2f(v1.y); vv[6]  = bfb2f(v1.z); vv[7]  = bfb2f(v1.w);
            vv[8] = bfb2f(v2.x); vv[9] = bfb2f(v2.y); vv[10] = bfb2f(v2.z); vv[11] = bfb2f(v2.w);
        }

        const int kj = rA;
        const int* mrow = gmask + (size_t)b * 144;
        #pragma unroll
        for (int r = 0; r < 4; ++r) {
            int qi = g * 4 + r;
            float s = sc[r] * 0.125f;
            if (kj >= 12) s = -INFINITY;
            else if (qi < 12 && mrow[qi * 12 + kj] == 0) s = -1e9f;
            float m = s;
            #pragma unroll
            for (int off = 1; off < 16; off <<= 1) m = fmaxf(m, __shfl_xor(m, off, 16));
            float e = __expf(s - m);
            float sum = e;
            #pragma unroll
            for (int off = 1; off < 16; off <<= 1) sum += __shfl_xor(sum, off, 16);
            if (qi < 12) probs[w][qi][kj] = e / sum;
        }

        #pragma unroll
        for (int qi = 0; qi < 12; ++qi) {
            const f32x4* pr = (const f32x4*)&probs[w][qi][0];
            f32x4 p0 = pr[0], p1 = pr[1], p2 = pr[2];
            float acc = 0.f;
            #pragma unroll
            for (int j = 0; j < 4; ++j) acc += p0[j] * vv[j] + p1[j] * vv[j + 4] + p2[j] * vv[j + 8];
            abuf[(bb * 12 + qi) * 520 + h * 64 + d] = f2bfb(acc);
        }
    }
    __syncthreads();

    {
        const short* Ws = (const short*)Wb;
        const int n_lane = w * 64 + rA;
        f32x4 acc[3][4] = {};
        #pragma unroll 4
        for (int kk = 0; kk < 16; ++kk) {
            int k0 = kk * 32 + g * 8;
            bf16x8 af0 = *(const bf16x8*)(abuf + (rA)      * 520 + k0);
            bf16x8 af1 = *(const bf16x8*)(abuf + (16 + rA) * 520 + k0);
            bf16x8 af2 = *(const bf16x8*)(abuf + (32 + rA) * 520 + k0);
            #pragma unroll
            for (int i = 0; i < 4; ++i) {
                bf16x8 bfg = *(const bf16x8*)(Ws + (size_t)(n_lane + i * 16) * NDM + k0);
                acc[0][i] = __builtin_amdgcn_mfma_f32_16x16x32_bf16(af0, bfg, acc[0][i], 0, 0, 0);
                acc[1][i] = __builtin_amdgcn_mfma_f32_16x16x32_bf16(af1, bfg, acc[1][i], 0, 0, 0);
                acc[2][i] = __builtin_amdgcn_mfma_f32_16x16x32_bf16(af2, bfg, acc[2][i], 0, 0, 0);
            }
        }
        float bias[4];
        #pragma unroll
        for (int i = 0; i < 4; ++i) bias[i] = gbo[w * 64 + i * 16 + rA];
        #pragma unroll
        for (int m = 0; m < 3; ++m) {
            #pragma unroll
            for (int i = 0; i < 4; ++i) {
                int n = w * 64 + i * 16 + rA;
                #pragma unroll
                for (int r = 0; r < 4; ++r) {
                    int mg  = m * 16 + g * 4 + r;
                    int bi  = mg / 12, qi = mg - bi * 12;
                    gout[(((size_t)(b0 + bi)) * NS + qi) * NDM + n] = acc[m][i][r] + bias[i];
                }
            }
        }
    }
}

// ---------------- Fallback: fused kernel (used if ws too small) ----------------
__global__ __launch_bounds__(512) void mha_fused4_kernel(
    const float* __restrict__ gq, const float* __restrict__ gk, const float* __restrict__ gv,
    const int* __restrict__ gmask, const float* __restrict__ gcw, const float* __restrict__ gcb,
    const __hip_bfloat16* __restrict__ Wb, const float* __restrict__ gbo,
    float* __restrict__ gout)
{
    __shared__ __align__(16) float xstage[NS][NDM];
    __shared__ __align__(16) short ovbuf[18432];
    __shared__ __align__(16) float probs[NH][16][16];
    __shared__ __align__(16) float wt[3][12][12];
    __shared__ __align__(16) float bconv[12];

    const int b   = blockIdx.x;
    const int tid = threadIdx.x;
    const int wv  = tid >> 6;
    const int ln  = tid & 63;
    const int h = wv, d = ln;

    if (tid < 432) {
        int t = tid / 144, rem = tid - t * 144;
        int s2 = rem / 12, s = rem - s2 * 12;
        wt[t][s2][s] = gcw[s * 36 + s2 * 3 + t];
    } else if (tid < 444) {
        bconv[tid - 432] = gcb[tid - 432];
    }

    const size_t xoff = (size_t)b * (NS * NDM);
    float vv[12];

    for (int t3 = 0; t3 < 3; ++t3) {
        const float* xb = ((t3 == 0) ? gq : (t3 == 1) ? gk : gv) + xoff;
        {
            const float4* s4 = (const float4*)xb;
            float4* dst4 = (float4*)&xstage[0][0];
            #pragma unroll
            for (int i = 0; i < 3; ++i) dst4[tid + i * 512] = s4[tid + i * 512];
        }
        __syncthreads();

        f32x4 o0 = *(const f32x4*)&bconv[0];
        f32x4 o1 = *(const f32x4*)&bconv[4];
        f32x4 o2 = *(const f32x4*)&bconv[8];
        #pragma unroll 4
        for (int s2 = 0; s2 < 12; ++s2) {
            float c  = xstage[s2][h * 64 + d];
            float cm = (h > 0) ? xstage[s2][(h - 1) * 64 + d] : 0.f;
            float cp = (h < 7) ? xstage[s2][(h + 1) * 64 + d] : 0.f;
            float n0 = c + cm + cp;
            float nm = __shfl_up(n0, 1);   if (d == 0)  nm = 0.f;
            float np = __shfl_down(n0, 1); if (d == 63) np = 0.f;
            const f32x4* w0 = (const f32x4*)&wt[0][s2][0];
            const f32x4* w1 = (const f32x4*)&wt[1][s2][0];
            const f32x4* w2 = (const f32x4*)&wt[2][s2][0];
            o0 += w0[0] * nm + w1[0] * n0 + w2[0] * np;
            o1 += w0[1] * nm + w1[1] * n0 + w2[1] * np;
            o2 += w0[2] * nm + w1[2] * n0 + w2[2] * np;
        }
        if (t3 < 2) {
            __hip_bfloat16* st = (__hip_bfloat16*)(ovbuf + (wv * 2 + t3) * 1152);
            #pragma unroll
            for (int s = 0; s < 4; ++s) st[s * 72 + d]       = __float2bfloat16(o0[s]);
            #pragma unroll
            for (int s = 0; s < 4; ++s) st[(s + 4) * 72 + d] = __float2bfloat16(o1[s]);
            #pragma unroll
            for (int s = 0; s < 4; ++s) st[(s + 8) * 72 + d] = __float2bfloat16(o2[s]);
            __syncthreads();
        } else {
            #pragma unroll
            for (int s = 0; s < 4; ++s) { vv[s] = o0[s]; vv[s + 4] = o1[s]; vv[s + 8] = o2[s]; }
        }
    }

    const short* qsp = ovbuf + (wv * 2 + 0) * 1152;
    const short* ksp = ovbuf + (wv * 2 + 1) * 1152;
    const int rA = ln & 15, g = ln >> 4;
    bf16x8 aq0 = *(const bf16x8*)(qsp + rA * 72 + g * 8);
    bf16x8 aq1 = *(const bf16x8*)(qsp + rA * 72 + 32 + g * 8);
    bf16x8 bk0 = *(const bf16x8*)(ksp + rA * 72 + g * 8);
    bf16x8 bk1 = *(const bf16x8*)(ksp + rA * 72 + 32 + g * 8);
    f32x4 sc = {0.f, 0.f, 0.f, 0.f};
    sc = __builtin_amdgcn_mfma_f32_16x16x32_bf16(aq0, bk0, sc, 0, 0, 0);
    sc = __builtin_amdgcn_mfma_f32_16x16x32_bf16(aq1, bk1, sc, 0, 0, 0);

    const int kj = rA;
    const int* mrow = gmask + (size_t)b * 144;
    #pragma unroll
    for (int r = 0; r < 4; ++r) {
        int qi = g * 4 + r;
        float s = sc[r] * 0.125f;
        if (kj >= 12) s = -INFINITY;
        else if (qi < 12 && mrow[qi * 12 + kj] == 0) s = -1e9f;
        float m = s;
        #pragma unroll
        for (int off = 1; off < 16; off <<= 1) m = fmaxf(m, __shfl_xor(m, off, 16));
        float e = __expf(s - m);
        float sum = e;
        #pragma unroll
        for (int off = 1; off < 16; off <<= 1) sum += __shfl_xor(sum, off, 16);
        probs[wv][qi][kj] = e / sum;
    }

    __syncthreads();

    __hip_bfloat16* ab = (__hip_bfloat16*)ovbuf;
    #pragma unroll
    for (int qi = 0; qi < 12; ++qi) {
        const f32x4* pr = (const f32x4*)&probs[wv][qi][0];
        f32x4 p0 = pr[0], p1 = pr[1], p2 = pr[2];
        float acc = 0.f;
        #pragma unroll
        for (int j = 0; j < 4; ++j) acc += p0[j] * vv[j] + p1[j] * vv[j + 4] + p2[j] * vv[j + 8];
        ab[qi * 520 + h * 64 + d] = __float2bfloat16(acc);
    }
    {
        unsigned* az = (unsigned*)(ovbuf + 12 * 520);
        for (int i = tid; i < 1040; i += 512) az[i] = 0u;
    }
    __syncthreads();

    {
        const short* Ws = (const short*)Wb;
        const short* As = ovbuf;
        f32x4 acc[4] = {};
        const int n_lane = wv * 64 + rA;
        #pragma unroll 4
        for (int kk = 0; kk < 16; ++kk) {
            int k0 = kk * 32 + g * 8;
            bf16x8 af = *(const bf16x8*)(As + rA * 520 + k0);
            #pragma unroll
            for (int i = 0; i < 4; ++i) {
                bf16x8 bfg = *(const bf16x8*)(Ws + (size_t)(n_lane + i * 16) * NDM + k0);
                acc[i] = __builtin_amdgcn_mfma_f32_16x16x32_bf16(af, bfg, acc[i], 0, 0, 0);
            }
        }
        float* outb = gout + (size_t)b * (NS * NDM);
        const int m0 = g * 4;
        #pragma unroll
        for (int i = 0; i < 4; ++i) {
            int n = wv * 64 + i * 16 + rA;
            float bias = gbo[n];
            #pragma unroll
            for (int r = 0; r < 4; ++r) {
                int m = m0 + r;
                if (m < 12) outb[m * NDM + n] = acc[i][r] + bias;
            }
        }
    }
}

extern "C" void kernel_launch(void* const* d_in, const int* in_sizes, int n_in,
                              void* d_out, int out_size, void* d_ws, size_t ws_size,
                              hipStream_t stream) {
    const float* q    = (const float*)d_in[0];
    const float* k    = (const float*)d_in[1];
    const float* v    = (const float*)d_in[2];
    const int*   mask = (const int*)d_in[3];
    const float* cw   = (const float*)d_in[4];
    const float* cb   = (const float*)d_in[5];
    const float* W    = (const float*)d_in[6];
    const float* bo   = (const float*)d_in[7];

    const size_t TEN = (size_t)NB * NH * NS * NDK * sizeof(short);
    const size_t REQ = 3 * TEN + (size_t)NDM * NDM * sizeof(short);

    if (ws_size >= REQ) {
        short* vc = (short*)d_ws;
        short* qc = vc + TEN / sizeof(short);
        short* kc = qc + TEN / sizeof(short);
        __hip_bfloat16* Wb = (__hip_bfloat16*)(kc + TEN / sizeof(short));

        hipLaunchKernelGGL(wcvt_kernel, dim3(512), dim3(512), 0, stream, W, Wb);
        hipLaunchKernelGGL(conv4_kernel, dim3(NB / 2, 3), dim3(256), 0, stream,
                           q, k, v, cw, cb, qc, kc, vc);
        hipLaunchKernelGGL(attn2_kernel, dim3(NB / 4), dim3(512), 0, stream,
                           qc, kc, vc, mask, Wb, bo, (float*)d_out);
    } else {
        __hip_bfloat16* Wb = (__hip_bfloat16*)d_ws;
        hipLaunchKernelGGL(wcvt_kernel, dim3(512), dim3(512), 0, stream, W, Wb);
        hipLaunchKernelGGL(mha_fused4_kernel, dim3(NB), dim3(512), 0, stream,
                           q, k, v, mask, cw, cb, Wb, bo, (float*)d_out);
    }
}